// Round 11
// baseline (186.674 us; speedup 1.0000x reference)
//
#include <hip/hip_runtime.h>

#define HW    96
#define NPIX  9216        // 96*96
#define NCH   64          // C
#define INNER 3
#define NDIL  3
#define BB    2           // batch
#define TOTPIX (BB * NPIX)   // 18432

typedef __attribute__((ext_vector_type(8))) short short8;            // 8 bf16
typedef __attribute__((ext_vector_type(8))) unsigned short ushort8;  // 8 bf16 raw
typedef __attribute__((ext_vector_type(4))) float f32x4;

__device__ __forceinline__ ushort f2bf_rne(float f) {
    unsigned u = __float_as_uint(f);
    u += 0x7fffu + ((u >> 16) & 1u);
    return (ushort)(u >> 16);
}
__device__ __forceinline__ float bf2f(ushort u) {
    return __uint_as_float((unsigned)u << 16);
}
// pack hi16(a),hi16(b) -> dword {bf16(b)<<16 | bf16(a)} (trunc; ratio-safe for P)
__device__ __forceinline__ unsigned pack_bf(float lo, float hi) {
    return __builtin_amdgcn_perm(__float_as_uint(hi), __float_as_uint(lo), 0x07060302u);
}

// ---------------------------------------------------------------------------
// Kernel 1: x_red = 1x1 conv (64 -> 3 channels)
// ---------------------------------------------------------------------------
__global__ void k_reduce(const float* __restrict__ x, const float* __restrict__ w_red,
                         const float* __restrict__ b_red, float* __restrict__ xred) {
    int pix = blockIdx.x * blockDim.x + threadIdx.x;
    if (pix >= TOTPIX) return;
    int b = pix / NPIX, n = pix % NPIX;
    float a0 = b_red[0], a1 = b_red[1], a2 = b_red[2];
    const float* xb = x + (size_t)b * NCH * NPIX + n;
    #pragma unroll
    for (int c = 0; c < NCH; ++c) {
        float xv = xb[(size_t)c * NPIX];
        a0 = fmaf(w_red[0 * NCH + c], xv, a0);
        a1 = fmaf(w_red[1 * NCH + c], xv, a1);
        a2 = fmaf(w_red[2 * NCH + c], xv, a2);
    }
    float* xr = xred + (size_t)b * INNER * NPIX + n;
    xr[0 * NPIX] = a0; xr[1 * NPIX] = a1; xr[2 * NPIX] = a2;
}

// ---------------------------------------------------------------------------
// Kernel 2a: features. thread = (pixel, dilation i3). Writes FT[j][pix] bf16,
// j = i3*18 + t*3 + o. Rows 54..63 never written — zero-weighted in k_fuse.
// ---------------------------------------------------------------------------
__global__ __launch_bounds__(256) void
k_feat(const float* __restrict__ xred, const float* __restrict__ w_dil,
       const float* __restrict__ b_dil, ushort* __restrict__ FT) {
    int gid = blockIdx.x * 256 + threadIdx.x;      // 3 * 18432 threads
    int i3 = gid / TOTPIX;                          // wave-uniform
    int pix = gid - i3 * TOTPIX;
    int b = pix / NPIX, n = pix % NPIX;
    int h = n / HW, w = n % HW;
    const float* xr = xred + (size_t)b * INNER * NPIX;
    int d = i3 + 1;

    float co[3] = {b_dil[i3 * 3 + 0], b_dil[i3 * 3 + 1], b_dil[i3 * 3 + 2]};
    #pragma unroll
    for (int ci = 0; ci < 3; ++ci) {
        const float* xo = xr + ci * NPIX;
        #pragma unroll
        for (int kh = 0; kh < 3; ++kh) {
            int hh = h + (kh - 1) * d;
            #pragma unroll
            for (int kw = 0; kw < 3; ++kw) {
                int ww = w + (kw - 1) * d;
                float v = ((unsigned)hh < HW && (unsigned)ww < HW) ? xo[hh * HW + ww] : 0.f;
                #pragma unroll
                for (int o = 0; o < 3; ++o)
                    co[o] = fmaf(w_dil[(9 * i3 + 3 * o + ci) * 9 + kh * 3 + kw], v, co[o]);
            }
        }
    }

    float tf[6][3];
    #pragma unroll
    for (int o = 0; o < 3; ++o) {
        const float* xo = xr + o * NPIX;
        tf[0][o] = xo[h * HW + w];
        tf[1][o] = xo[h * HW + (HW - 1 - w)];
        tf[2][o] = xo[(HW - 1 - h) * HW + w];
        tf[3][o] = xo[w * HW + (HW - 1 - h)];
        tf[4][o] = xo[(HW - 1 - h) * HW + (HW - 1 - w)];
        tf[5][o] = xo[(HW - 1 - w) * HW + h];
    }

    #pragma unroll
    for (int t = 0; t < 6; ++t)
        #pragma unroll
        for (int o = 0; o < 3; ++o) {
            int j = i3 * 18 + t * 3 + o;
            FT[(size_t)j * TOTPIX + pix] = f2bf_rne(co[o] * tf[t][o]);
        }
}

// ---------------------------------------------------------------------------
// Kernel 2b: fuse conv as MFMA GEMM, 64 px/block (grid 288).
// tok is written PRE-SCALED by sqrt(0.125*log2e) (serves as both Q and K in
// k_attn — product scale folds to 0.125*log2e). tokT stays unscaled (V).
// ---------------------------------------------------------------------------
__global__ __launch_bounds__(256) void
k_fuse(const ushort* __restrict__ FT, const float* __restrict__ w_fuse,
       const float* __restrict__ b_fuse, ushort* __restrict__ tok,
       ushort* __restrict__ tokT) {
    __shared__ ushort wpad[64 * 72];     // [c][j pad 72]
    __shared__ float  bsh[64];
    __shared__ ushort tile[64 * 72];     // [c][64 px + 8 pad]

    int tid = threadIdx.x;
    for (int i = tid; i < 64 * 64; i += 256) {
        int c = i >> 6, j = i & 63;
        wpad[c * 72 + j] = (j < 54) ? f2bf_rne(w_fuse[c * 54 + j]) : (ushort)0;
    }
    if (tid < 64) bsh[tid] = b_fuse[tid];
    __syncthreads();

    int wv = tid >> 6, lane = tid & 63, quad = lane >> 4, l15 = lane & 15;
    int px0 = blockIdx.x * 64;

    short8 af[4][2];
    #pragma unroll
    for (int m = 0; m < 4; ++m)
        #pragma unroll
        for (int kc = 0; kc < 2; ++kc)
            af[m][kc] = *(const short8*)&wpad[(16 * m + l15) * 72 + quad * 8 + 32 * kc];

    f32x4 acc[4];
    #pragma unroll
    for (int m = 0; m < 4; ++m) acc[m] = (f32x4){0.f, 0.f, 0.f, 0.f};

    int px = px0 + wv * 16 + l15;
    #pragma unroll
    for (int kc = 0; kc < 2; ++kc) {
        short8 bf;
        #pragma unroll
        for (int jj = 0; jj < 8; ++jj)
            bf[jj] = (short)FT[(size_t)(quad * 8 + jj + 32 * kc) * TOTPIX + px];
        #pragma unroll
        for (int m = 0; m < 4; ++m)
            acc[m] = __builtin_amdgcn_mfma_f32_16x16x32_bf16(af[m][kc], bf, acc[m], 0, 0, 0);
    }

    #pragma unroll
    for (int m = 0; m < 4; ++m)
        #pragma unroll
        for (int r = 0; r < 4; ++r) {
            int c = 16 * m + quad * 4 + r;
            tile[c * 72 + wv * 16 + l15] = f2bf_rne(acc[m][r] + bsh[c]);
        }
    __syncthreads();

    const float SQS = 0.424660891f;      // sqrt(0.125 * log2(e))
    int b0 = px0 / NPIX, n0 = px0 % NPIX;
    {   // tok[b][n][c], scaled by SQS
        int lp = tid >> 2, part = tid & 3;
        ushort row[16];
        #pragma unroll
        for (int k = 0; k < 16; ++k)
            row[k] = f2bf_rne(bf2f(tile[(part * 16 + k) * 72 + lp]) * SQS);
        ushort* dst = tok + ((size_t)b0 * NPIX + n0 + lp) * NCH + part * 16;
        *(ushort8*)&dst[0] = *(const ushort8*)&row[0];
        *(ushort8*)&dst[8] = *(const ushort8*)&row[8];
    }
    {   // tokT[b][c][n], unscaled (V operand)
        int c = tid >> 2, seg = tid & 3;
        ushort* dst = tokT + ((size_t)b0 * NCH + c) * NPIX + n0 + seg * 16;
        *(ushort8*)&dst[0] = *(const ushort8*)&tile[c * 72 + seg * 16];
        *(ushort8*)&dst[8] = *(const ushort8*)&tile[c * 72 + seg * 16 + 8];
    }
}

// ---------------------------------------------------------------------------
// Kernel 3: MFMA flash attention — R10 structure with S computed in two
// 16-key halves to cut peak register liveness (S 16 regs, kf 8 regs; vf
// loaded after softmax). Same global traffic / MFMA count / exp2 count as
// R10's 101 µs kernel; goal is 3 waves/SIMD under launch_bounds(256,3).
// tok is pre-scaled (Q·K product scale = 0.125*log2e) -> qf is a raw load.
// Fixed exp2 base FM; pt per-wave [64][40]; pacc bf16 [b][p][c][n].
// ---------------------------------------------------------------------------
__global__ __launch_bounds__(256, 3) void
k_attn(const ushort* __restrict__ tok, const ushort* __restrict__ tokT,
       float* __restrict__ pl, ushort* __restrict__ pacc, int P, int KP) {
    __shared__ ushort pt[4][64 * 40];   // per-wave P^T [q][32key + 8 pad], 20 KB

    const int QW = NPIX / 256;          // 36 query chunks per batch
    int bid = blockIdx.x;
    int qc = bid % QW; int rest = bid / QW;
    int p = rest % P;  int b = rest / P;
    int tid = threadIdx.x;
    int wv = tid >> 6, lane = tid & 63;
    int quad = lane >> 4, l15 = lane & 15;

    const ushort* tb  = tok  + (size_t)b * NPIX * NCH;
    const ushort* tbT = tokT + (size_t)b * NCH * NPIX;
    int qwave = qc * 256 + wv * 64;

    // Q fragments: direct raw loads (scale pre-folded into tok).
    short8 qf[4][2];
    #pragma unroll
    for (int n = 0; n < 4; ++n) {
        const ushort* qr = tb + (size_t)(qwave + 16 * n + l15) * NCH + quad * 8;
        qf[n][0] = *(const short8*)(qr);
        qf[n][1] = *(const short8*)(qr + 32);
    }

    f32x4 O[4][4];                      // O^T acc: D[c=16m+quad*4+reg][q=16n+l15]
    #pragma unroll
    for (int m = 0; m < 4; ++m)
        #pragma unroll
        for (int n = 0; n < 4; ++n) O[m][n] = (f32x4){0.f, 0.f, 0.f, 0.f};
    float lrun[4] = {0.f, 0.f, 0.f, 0.f};

    const float FM = 16.0f;             // fixed exp2-domain shift

    int k0 = p * KP;
    for (int kb = 0; kb < KP; kb += 32) {
        int kbase = k0 + kb;

        // Two 16-key halves: S[1][4] (16 regs) live at a time.
        #pragma unroll
        for (int m2 = 0; m2 < 2; ++m2) {
            const ushort* kr = tb + (size_t)(kbase + 16 * m2 + l15) * NCH + quad * 8;
            short8 kf0 = *(const short8*)(kr);
            short8 kf1 = *(const short8*)(kr + 32);
            f32x4 S[4];
            #pragma unroll
            for (int n = 0; n < 4; ++n) S[n] = (f32x4){0.f, 0.f, 0.f, 0.f};
            #pragma unroll
            for (int n = 0; n < 4; ++n) {
                S[n] = __builtin_amdgcn_mfma_f32_16x16x32_bf16(kf0, qf[n][0], S[n], 0, 0, 0);
                S[n] = __builtin_amdgcn_mfma_f32_16x16x32_bf16(kf1, qf[n][1], S[n], 0, 0, 0);
            }
            // softmax numerators for these 16 keys, fixed base
            #pragma unroll
            for (int n = 0; n < 4; ++n) {
                int q = 16 * n + l15;
                float p0 = __builtin_amdgcn_exp2f(S[n][0] - FM);
                float p1 = __builtin_amdgcn_exp2f(S[n][1] - FM);
                float p2 = __builtin_amdgcn_exp2f(S[n][2] - FM);
                float p3 = __builtin_amdgcn_exp2f(S[n][3] - FM);
                lrun[n] += (p0 + p1) + (p2 + p3);
                // key_local = 16*m2 + quad*4 + reg
                *(uint2*)&pt[wv][q * 40 + m2 * 16 + quad * 4] =
                    make_uint2(pack_bf(p0, p1), pack_bf(p2, p3));
            }
        }

        // V^T fragments (A[ch][key]) — loaded after softmax to cap liveness
        short8 vf[4];
        #pragma unroll
        for (int mc = 0; mc < 4; ++mc)
            vf[mc] = *(const short8*)(tbT + (size_t)(16 * mc + l15) * NPIX + kbase + quad * 8);

        // O^T += V^T·P^T (K=32): B[k=quad*8+j][n=q] from padded pt (same wave)
        #pragma unroll
        for (int n = 0; n < 4; ++n) {
            int q = 16 * n + l15;
            short8 bfr = *(const short8*)&pt[wv][q * 40 + quad * 8];
            #pragma unroll
            for (int mc = 0; mc < 4; ++mc)
                O[mc][n] = __builtin_amdgcn_mfma_f32_16x16x32_bf16(vf[mc], bfr,
                                                                   O[mc][n], 0, 0, 0);
        }
    }

    #pragma unroll
    for (int n = 0; n < 4; ++n) {       // disjoint key subsets per quad
        lrun[n] += __shfl_xor(lrun[n], 16, 64);
        lrun[n] += __shfl_xor(lrun[n], 32, 64);
    }
    size_t bp = (size_t)b * P + p;
    if (quad == 0) {
        #pragma unroll
        for (int n = 0; n < 4; ++n)
            pl[bp * NPIX + qwave + 16 * n + l15] = lrun[n];
    }
    // pacc[b][p][c][n]: per (n,m,r) scalar 2B stores; across l15 lanes each
    // (m,r) is a 32B contiguous segment -> sector-aligned.
    #pragma unroll
    for (int n = 0; n < 4; ++n) {
        int qg = qwave + 16 * n + l15;
        #pragma unroll
        for (int m = 0; m < 4; ++m) {
            #pragma unroll
            for (int r = 0; r < 4; ++r) {
                int c = 16 * m + quad * 4 + r;
                pacc[(bp * NCH + c) * NPIX + qg] = f2bf_rne(O[m][n][r]);
            }
        }
    }
}

// ---------------------------------------------------------------------------
// Kernel 3b: Linv[b][n] = 0.2 / sum_p pl[b][p][n]
// ---------------------------------------------------------------------------
__global__ void k_norm(const float* __restrict__ pl, float* __restrict__ linv, int P) {
    int idx = blockIdx.x * blockDim.x + threadIdx.x;
    if (idx >= TOTPIX) return;
    int b = idx / NPIX, n = idx % NPIX;
    float L = 0.f;
    for (int p = 0; p < P; ++p) L += pl[((size_t)b * P + p) * NPIX + n];
    linv[idx] = 0.2f / L;
}

// ---------------------------------------------------------------------------
// Kernel 4: fully-coalesced combine. thread = (b, c, 8-n segment):
// o[n] = sum_p pacc[b][p][c][n] (ushort8 rows), out = x + Linv[n]*o[n].
// ---------------------------------------------------------------------------
__global__ void k_combine(const float* __restrict__ x, const float* __restrict__ linv,
                          const ushort* __restrict__ pacc, float* __restrict__ out,
                          int P) {
    int gid = blockIdx.x * blockDim.x + threadIdx.x;   // (b*NCH + c)*1152 + seg
    if (gid >= BB * NCH * (NPIX / 8)) return;
    int seg = gid % (NPIX / 8);
    int bc  = gid / (NPIX / 8);
    int b = bc / NCH;
    int n0 = seg * 8;
    float o[8] = {0.f, 0.f, 0.f, 0.f, 0.f, 0.f, 0.f, 0.f};
    for (int p = 0; p < P; ++p) {
        ushort8 t = *(const ushort8*)(pacc +
            (((size_t)b * P + p) * NCH + (bc % NCH)) * NPIX + n0);
        #pragma unroll
        for (int e = 0; e < 8; ++e) o[e] += bf2f(t[e]);
    }
    const float* lv = linv + (size_t)b * NPIX + n0;
    const float* xb = x + (size_t)bc * NPIX + n0;
    float* ob = out + (size_t)bc * NPIX + n0;
    #pragma unroll
    for (int e = 0; e < 8; ++e)
        ob[e] = fmaf(lv[e], o[e], xb[e]);
}

// ---------------------------------------------------------------------------
extern "C" void kernel_launch(void* const* d_in, const int* in_sizes, int n_in,
                              void* d_out, int out_size, void* d_ws, size_t ws_size,
                              hipStream_t stream) {
    const float* x      = (const float*)d_in[0];
    const float* w_red  = (const float*)d_in[1];
    const float* b_red  = (const float*)d_in[2];
    const float* w_dil  = (const float*)d_in[3];
    const float* b_dil  = (const float*)d_in[4];
    const float* w_fuse = (const float*)d_in[5];
    const float* b_fuse = (const float*)d_in[6];
    float* out = (float*)d_out;

    // ws: xred f32 | FT bf16 | tok bf16 | tokT bf16 | pl f32 | linv f32 | pacc bf16
    const size_t XRED_N = (size_t)BB * INNER * NPIX;
    const size_t FT_N   = (size_t)64 * TOTPIX;
    const size_t TOK_N  = (size_t)BB * NPIX * NCH;
    const size_t HEAD_B = XRED_N * 4 + (FT_N + 2 * TOK_N) * 2 + TOTPIX * 4;
    int P = 0;
    const int cands[5] = {16, 8, 4, 2, 1};   // KP = 9216/P multiple of 32 for all
    for (int ci = 0; ci < 5; ++ci) {
        int cp = cands[ci];
        size_t need = HEAD_B + (size_t)BB * cp * NPIX * (4 + NCH * 2);
        if (ws_size >= need) { P = cp; break; }
    }
    if (P == 0) return;

    float*  xred = (float*)d_ws;
    ushort* FT   = (ushort*)(xred + XRED_N);
    ushort* tok  = FT + FT_N;
    ushort* tokT = tok + TOK_N;
    float*  pl   = (float*)(tokT + TOK_N);
    float*  linv = pl + (size_t)BB * P * NPIX;
    ushort* pacc = (ushort*)(linv + TOTPIX);

    k_reduce <<<(TOTPIX + 255) / 256, 256, 0, stream>>>(x, w_red, b_red, xred);
    k_feat   <<<3 * TOTPIX / 256, 256, 0, stream>>>(xred, w_dil, b_dil, FT);
    k_fuse   <<<TOTPIX / 64, 256, 0, stream>>>(FT, w_fuse, b_fuse, tok, tokT);
    k_attn   <<<BB * P * (NPIX / 256), 256, 0, stream>>>(tok, tokT, pl, pacc,
                                                         P, NPIX / P);
    k_norm   <<<(TOTPIX + 255) / 256, 256, 0, stream>>>(pl, linv, P);
    k_combine<<<(BB * NCH * (NPIX / 8) + 255) / 256, 256, 0, stream>>>(x, linv, pacc,
                                                                       out, P);
}